// Round 1
// 762.591 us; speedup vs baseline: 1.1246x; 1.1246x over previous
//
#include <hip/hip_runtime.h>

namespace {

constexpr int NP = 100000;
constexpr int NS = 10000;
constexpr int EC = 1600000;
constexpr int LC = 1000000;

// bucketed CSR build params
constexpr int SH_S = 6;                        // se nodes per bucket = 64
constexpr int SH_P = 9;                        // pd nodes per bucket = 512
constexpr int NBS = (NS + 63) >> SH_S;         // 157 buckets
constexpr int NBP = (NP + 511) >> SH_P;        // 196 buckets
constexpr int CHUNK = 8192;
constexpr int NBLK = (EC + CHUNK - 1) / CHUNK; // 196

typedef short i16x8 __attribute__((ext_vector_type(8)));
typedef float f32x4 __attribute__((ext_vector_type(4)));

__device__ inline ushort f2bf(float f) {  // RNE fp32->bf16
  unsigned u = __float_as_uint(f);
  u += 0x7FFFu + ((u >> 16) & 1u);
  return (ushort)(u >> 16);
}
__device__ inline float bflo(uint v) { return __uint_as_float(v << 16); }
__device__ inline float bfhi(uint v) { return __uint_as_float(v & 0xffff0000u); }

// ---------------- CSR build: bucketed counting sort ----------------

__global__ void __launch_bounds__(256) k_bcount(const int* __restrict__ src,
                                                const int* __restrict__ dst,
                                                int* __restrict__ bcntS,
                                                int* __restrict__ bcntP, int E) {
  __shared__ int hS[256];
  __shared__ int hP[256];
  const int t = threadIdx.x;
  hS[t] = 0;
  hP[t] = 0;
  __syncthreads();
  const int base = blockIdx.x * CHUNK;
  const int end = min(base + CHUNK, E);
  for (int e = base + t; e < end; e += 256) {
    atomicAdd(&hS[dst[e] >> SH_S], 1);
    atomicAdd(&hP[src[e] >> SH_P], 1);
  }
  __syncthreads();
  if (t < NBS && hS[t]) atomicAdd(&bcntS[t], hS[t]);
  if (t < NBP && hP[t]) atomicAdd(&bcntP[t], hP[t]);
}

__global__ void __launch_bounds__(256) k_bscan(const int* __restrict__ bcntS,
                                               const int* __restrict__ bcntP,
                                               int* __restrict__ gbaseS,
                                               int* __restrict__ gbaseP,
                                               int* __restrict__ gcurS,
                                               int* __restrict__ gcurP) {
  __shared__ int s[256];
  const int t = threadIdx.x;
  int v = (t < NBS) ? bcntS[t] : 0;
  s[t] = v;
  __syncthreads();
  for (int off = 1; off < 256; off <<= 1) {
    int u = (t >= off) ? s[t - off] : 0;
    __syncthreads();
    s[t] += u;
    __syncthreads();
  }
  if (t < NBS) {
    int ex = s[t] - v;
    gbaseS[t] = ex;
    gcurS[t] = ex;
  }
  __syncthreads();
  v = (t < NBP) ? bcntP[t] : 0;
  s[t] = v;
  __syncthreads();
  for (int off = 1; off < 256; off <<= 1) {
    int u = (t >= off) ? s[t - off] : 0;
    __syncthreads();
    s[t] += u;
    __syncthreads();
  }
  if (t < NBP) {
    int ex = s[t] - v;
    gbaseP[t] = ex;
    gcurP[t] = ex;
  }
}

// packed tmp entries: S side = (d&63)<<17 | s  (s < 2^17)
//                     P side = (s&511)<<14 | d (d < 2^14)
__global__ void __launch_bounds__(256) k_bscatter(const int* __restrict__ src,
                                                  const int* __restrict__ dst,
                                                  int* __restrict__ gcurS,
                                                  int* __restrict__ gcurP,
                                                  int* __restrict__ tmpS,
                                                  int* __restrict__ tmpP, int E) {
  __shared__ int hS[256];
  __shared__ int hP[256];
  const int t = threadIdx.x;
  hS[t] = 0;
  hP[t] = 0;
  __syncthreads();
  const int base = blockIdx.x * CHUNK;
  const int end = min(base + CHUNK, E);
  for (int e = base + t; e < end; e += 256) {
    atomicAdd(&hS[dst[e] >> SH_S], 1);
    atomicAdd(&hP[src[e] >> SH_P], 1);
  }
  __syncthreads();
  int myBaseS = 0, myBaseP = 0;
  if (t < NBS) {
    int c = hS[t];
    myBaseS = c ? atomicAdd(&gcurS[t], c) : 0;
  }
  if (t < NBP) {
    int c = hP[t];
    myBaseP = c ? atomicAdd(&gcurP[t], c) : 0;
  }
  __syncthreads();
  if (t < NBS) hS[t] = myBaseS;
  if (t < NBP) hP[t] = myBaseP;
  __syncthreads();
  for (int e = base + t; e < end; e += 256) {
    const int d = dst[e];
    const int s = src[e];
    int p = atomicAdd(&hS[d >> SH_S], 1);
    tmpS[p] = ((d & 63) << 17) | s;
    int q = atomicAdd(&hP[s >> SH_P], 1);
    tmpP[q] = ((s & 511) << 14) | d;
  }
}

template <int NN, int LBITS>
__global__ void __launch_bounds__(256) k_bfinal(const int* __restrict__ tmp,
                                                const int* __restrict__ gbase,
                                                const int* __restrict__ bcnt,
                                                int shift, int Nnodes,
                                                int* __restrict__ rowptr,
                                                int* __restrict__ deg,
                                                int* __restrict__ col) {
  __shared__ int ldeg[NN];
  __shared__ int lscan[512];
  const int b = blockIdx.x;
  const int t = threadIdx.x;
  const int n0 = b << shift;
  const int base = gbase[b];
  const int cnt = bcnt[b];
  for (int i = t; i < NN; i += 256) ldeg[i] = 0;
  __syncthreads();
  for (int j = t; j < cnt; j += 256) atomicAdd(&ldeg[tmp[base + j] >> LBITS], 1);
  __syncthreads();
  for (int i = t; i < 512; i += 256) lscan[i] = (i < NN) ? ldeg[i] : 0;
  __syncthreads();
  for (int off = 1; off < 512; off <<= 1) {
    const int i0 = t, i1 = t + 256;
    const int v0 = (i0 >= off) ? lscan[i0 - off] : 0;
    const int v1 = (i1 >= off) ? lscan[i1 - off] : 0;
    __syncthreads();
    lscan[i0] += v0;
    lscan[i1] += v1;
    __syncthreads();
  }
  for (int i = t; i < NN; i += 256) {
    const int n = n0 + i;
    if (n < Nnodes) {
      const int dg = ldeg[i];
      rowptr[n] = base + lscan[i] - dg;
      deg[n] = dg;
    }
  }
  __syncthreads();
  for (int i = t; i < NN; i += 256) lscan[i] -= ldeg[i];
  __syncthreads();
  for (int j = t; j < cnt; j += 256) {
    const int v = tmp[base + j];
    const int p = atomicAdd(&lscan[v >> LBITS], 1);
    col[base + p] = v & ((1 << LBITS) - 1);
  }
}

// ---------------- weight transpose+cvt prep: Wt[n][k] (bf16) = W[k][n] ----------------

struct WtJob {
  const float* src;  // [K][64] fp32
  ushort* dst;       // row n at dst + n*stride + off
  int K;
  int stride;
  int off;
};
struct WtJobs {
  WtJob j[10];
};

__global__ void __launch_bounds__(256) k_wt_all(WtJobs jobs) {
  int e = blockIdx.x * 256 + threadIdx.x;
#pragma unroll
  for (int i = 0; i < 10; i++) {
    const int K = jobs.j[i].K;
    const int sz = K * 64;
    if (e < sz) {
      const int n = e / K;
      const int k = e - n * K;
      jobs.j[i].dst[(size_t)n * jobs.j[i].stride + jobs.j[i].off + k] =
          f2bf(jobs.j[i].src[(size_t)k * 64 + n]);
      return;
    }
    e -= sz;
  }
}

// ---------------- dual-job MFMA GEMM ----------------
// out[M x 64] = act(A[M x K] @ W[K x 64] + bias (+ emb))
// A = A0 (cols 0..KA0) | A1 (cols KA0..K); fp32 (cvt inline) or bf16 direct.
// Wt: bf16, [64 n][K k] row-major (pre-transposed).
// Block: 256 thr = 4 waves; 64 rows x 64 cols per block; K-step 64.
// Two jobs in one grid: blocks < ja.nblk run ja, rest run jb.

struct GJob {
  const void* A0;
  const void* A1;
  int KA0, sA0, sA1, K;
  const ushort* Wt;
  const float* bias;
  const float* emb;
  const int* nid;
  void* out;
  int M;
  int nblk;
};

template <bool RELU, bool EMB, bool ABF16, bool OBF16>
__global__ void __launch_bounds__(256) k_mgemm2(GJob ja, GJob jb) {
  __shared__ ushort Xs[64 * 72];
  __shared__ ushort Ws[64 * 72];
  const bool sec = (int)blockIdx.x >= ja.nblk;
  const GJob j = sec ? jb : ja;
  const int bid = sec ? ((int)blockIdx.x - ja.nblk) : (int)blockIdx.x;
  const int t = threadIdx.x;
  const int row0 = bid * 64;
  const int lane = t & 63;
  const int w = t >> 6;
  const int m16 = lane & 15;
  const int q = lane >> 4;
  const int M = j.M;
  const int K = j.K;
  const int KA0 = j.KA0;

  f32x4 acc[4];
#pragma unroll
  for (int nt = 0; nt < 4; nt++) acc[nt] = {0.f, 0.f, 0.f, 0.f};

  const int ksteps = K >> 6;
  for (int ks = 0; ks < ksteps; ks++) {
    const int k0 = ks << 6;
    uint4 wv[2];
#pragma unroll
    for (int i = 0; i < 2; i++) {
      const int u = t + i * 256;
      const int n = u >> 3;
      const int kk8 = (u & 7) << 3;
      wv[i] = *reinterpret_cast<const uint4*>(j.Wt + (size_t)n * K + k0 + kk8);
    }
    if constexpr (ABF16) {
      // A is bf16: 16B loads, straight copy into padded LDS
      uint4 xv[2];
#pragma unroll
      for (int i = 0; i < 2; i++) {
        const int u = t + i * 256;
        const int row = u >> 3;
        const int k8 = (u & 7) << 3;
        const int gr = min(row0 + row, M - 1);
        const int kk = k0 + k8;
        const ushort* sp = (kk < KA0)
                               ? ((const ushort*)j.A0 + (size_t)gr * j.sA0 + kk)
                               : ((const ushort*)j.A1 + (size_t)gr * j.sA1 + (kk - KA0));
        xv[i] = *reinterpret_cast<const uint4*>(sp);
      }
      __syncthreads();
#pragma unroll
      for (int i = 0; i < 2; i++) {
        const int u = t + i * 256;
        const int row = u >> 3;
        const int k8 = (u & 7) << 3;
        *reinterpret_cast<uint4*>(&Xs[row * 72 + k8]) = xv[i];
      }
    } else {
      // A is fp32: load float4, cvt to bf16 into LDS
      float4 xv[4];
#pragma unroll
      for (int i = 0; i < 4; i++) {
        const int u = t + i * 256;
        const int row = u >> 4;
        const int k4 = (u & 15) << 2;
        const int gr = min(row0 + row, M - 1);
        const int kk = k0 + k4;
        const float* sp = (kk < KA0)
                              ? ((const float*)j.A0 + (size_t)gr * j.sA0 + kk)
                              : ((const float*)j.A1 + (size_t)gr * j.sA1 + (kk - KA0));
        xv[i] = *reinterpret_cast<const float4*>(sp);
      }
      __syncthreads();
#pragma unroll
      for (int i = 0; i < 4; i++) {
        const int u = t + i * 256;
        const int row = u >> 4;
        const int k4 = (u & 15) << 2;
        ushort4 o;
        o.x = f2bf(xv[i].x);
        o.y = f2bf(xv[i].y);
        o.z = f2bf(xv[i].z);
        o.w = f2bf(xv[i].w);
        *reinterpret_cast<ushort4*>(&Xs[row * 72 + k4]) = o;
      }
    }
#pragma unroll
    for (int i = 0; i < 2; i++) {
      const int u = t + i * 256;
      const int n = u >> 3;
      const int kk8 = (u & 7) << 3;
      *reinterpret_cast<uint4*>(&Ws[n * 72 + kk8]) = wv[i];
    }
    __syncthreads();

    const ushort* ap = &Xs[(w * 16 + m16) * 72 + q * 8];
    const i16x8 a0 = *reinterpret_cast<const i16x8*>(ap);
    const i16x8 a1 = *reinterpret_cast<const i16x8*>(ap + 32);
#pragma unroll
    for (int nt = 0; nt < 4; nt++) {
      const ushort* bp = &Ws[(nt * 16 + m16) * 72 + q * 8];
      const i16x8 b0 = *reinterpret_cast<const i16x8*>(bp);
      const i16x8 b1 = *reinterpret_cast<const i16x8*>(bp + 32);
      acc[nt] = __builtin_amdgcn_mfma_f32_16x16x32_bf16(a0, b0, acc[nt], 0, 0, 0);
      acc[nt] = __builtin_amdgcn_mfma_f32_16x16x32_bf16(a1, b1, acc[nt], 0, 0, 0);
    }
    __syncthreads();
  }

  // epilogue: C/D layout col=lane&15, row=q*4+reg
  int grow[4];
  int nrow[4];
#pragma unroll
  for (int r = 0; r < 4; r++) {
    grow[r] = row0 + w * 16 + q * 4 + r;
    nrow[r] = (EMB && grow[r] < M) ? j.nid[grow[r]] : 0;
  }
#pragma unroll
  for (int nt = 0; nt < 4; nt++) {
    const int colv = nt * 16 + m16;
    const float bv = j.bias[colv];
#pragma unroll
    for (int r = 0; r < 4; r++) {
      if (grow[r] < M) {
        float v = acc[nt][r] + bv;
        if (EMB) v += j.emb[(size_t)nrow[r] * 64 + colv];
        if (RELU) v = fmaxf(v, 0.f);
        if (OBF16)
          ((ushort*)j.out)[(size_t)grow[r] * 64 + colv] = f2bf(v);
        else
          ((float*)j.out)[(size_t)grow[r] * 64 + colv] = v;
      }
    }
  }
}

// ---------------- dual-direction aggregation: mean over CSR neighbors (bf16) ------
// One wave per dst node; lane c in [0,32) handles channels 2c,2c+1 (uint = 2 bf16);
// lane halves process alternate edges; halves combined with one shfl_xor(32).

__global__ void __launch_bounds__(256) k_agg2(
    const ushort* __restrict__ hS,  // source rows for se-side agg ([NP][64])
    const ushort* __restrict__ hP,  // source rows for pd-side agg ([NS][64])
    const int* __restrict__ rpS, const int* __restrict__ degS, const int* __restrict__ colS,
    const int* __restrict__ rpP, const int* __restrict__ degP, const int* __restrict__ colP,
    ushort* __restrict__ outS,  // [NS][64]
    ushort* __restrict__ outP   // [NP][64]
) {
  int g = blockIdx.x * 4 + (threadIdx.x >> 6);
  const uint* hu;
  const int* rp;
  const int* deg;
  const int* col;
  uint* out;
  int node;
  if (g < NS) {
    hu = (const uint*)hS; rp = rpS; deg = degS; col = colS; out = (uint*)outS;
    node = g;
  } else {
    node = g - NS;
    if (node >= NP) return;
    hu = (const uint*)hP; rp = rpP; deg = degP; col = colP; out = (uint*)outP;
  }
  const int lane = threadIdx.x & 63;
  const int c = lane & 31;
  const int half = lane >> 5;
  const int beg = rp[node];
  const int cnt = deg[node];
  float a0 = 0.f, a1 = 0.f;
  int jj = 0;
  for (; jj + 16 <= cnt; jj += 16) {
    int n[8];
#pragma unroll
    for (int u = 0; u < 8; u++) n[u] = col[beg + jj + 2 * u + half];
#pragma unroll
    for (int u = 0; u < 8; u++) {
      const uint v = hu[(size_t)n[u] * 32 + c];
      a0 += bflo(v);
      a1 += bfhi(v);
    }
  }
  for (; jj + 2 <= cnt; jj += 2) {
    const uint v = hu[(size_t)col[beg + jj + half] * 32 + c];
    a0 += bflo(v);
    a1 += bfhi(v);
  }
  if (jj < cnt && half == 0) {
    const uint v = hu[(size_t)col[beg + jj] * 32 + c];
    a0 += bflo(v);
    a1 += bfhi(v);
  }
  a0 += __shfl_xor(a0, 32);
  a1 += __shfl_xor(a1, 32);
  if (half == 0) {
    const float d = (cnt > 0) ? (float)cnt : 1.f;
    const uint o = (uint)f2bf(a0 / d) | ((uint)f2bf(a1 / d) << 16);
    out[(size_t)node * 32 + c] = o;
  }
}

// ---------------- classifier (+ fused label copy) ----------------

__global__ void __launch_bounds__(256) k_classify(const float* __restrict__ pd2,
                                                  const float* __restrict__ se2,
                                                  const int* __restrict__ i0,
                                                  const int* __restrict__ i1,
                                                  const float* __restrict__ elabel,
                                                  float* __restrict__ outF, int L,
                                                  int nClsBlk) {
  if ((int)blockIdx.x >= nClsBlk) {
    const int i = ((int)blockIdx.x - nClsBlk) * 256 + threadIdx.x;
    if (i < L / 4)
      reinterpret_cast<float4*>(outF + L)[i] =
          reinterpret_cast<const float4*>(elabel)[i];
    return;
  }
  const int e = blockIdx.x * 16 + (threadIdx.x >> 4);
  if (e >= L) return;
  const int l16 = threadIdx.x & 15;
  const int a = i0[e];
  const int b = i1[e];
  const float4 va = *reinterpret_cast<const float4*>(&pd2[(size_t)a * 64 + l16 * 4]);
  const float4 vb = *reinterpret_cast<const float4*>(&se2[(size_t)b * 64 + l16 * 4]);
  float v = va.x * vb.x + va.y * vb.y + va.z * vb.z + va.w * vb.w;
  v += __shfl_xor(v, 1, 16);
  v += __shfl_xor(v, 2, 16);
  v += __shfl_xor(v, 4, 16);
  v += __shfl_xor(v, 8, 16);
  if (l16 == 0) outF[e] = v;
}

}  // namespace

extern "C" void kernel_launch(void* const* d_in, const int* in_sizes, int n_in,
                              void* d_out, int out_size, void* d_ws, size_t ws_size,
                              hipStream_t stream) {
  (void)in_sizes; (void)n_in; (void)out_size; (void)ws_size;
  const float* x_pd = (const float*)d_in[0];
  const float* x_se = (const float*)d_in[1];
  const int* nid_pd = (const int*)d_in[2];
  const int* nid_se = (const int*)d_in[3];
  const int* eidx = (const int*)d_in[4];
  const int* elidx = (const int*)d_in[5];
  const float* elabel = (const float*)d_in[6];
  const float* W_pd = (const float*)d_in[7];
  const float* b_pd = (const float*)d_in[8];
  const float* W_se = (const float*)d_in[9];
  const float* b_se = (const float*)d_in[10];
  const float* emb_pd = (const float*)d_in[11];
  const float* emb_se = (const float*)d_in[12];
  const float* c1_p2s_Wl = (const float*)d_in[13];
  const float* c1_p2s_bl = (const float*)d_in[14];
  const float* c1_p2s_Wr = (const float*)d_in[15];
  const float* c1_s2p_Wl = (const float*)d_in[16];
  const float* c1_s2p_bl = (const float*)d_in[17];
  const float* c1_s2p_Wr = (const float*)d_in[18];
  const float* c2_p2s_Wl = (const float*)d_in[19];
  const float* c2_p2s_bl = (const float*)d_in[20];
  const float* c2_p2s_Wr = (const float*)d_in[21];
  const float* c2_s2p_Wl = (const float*)d_in[22];
  const float* c2_s2p_bl = (const float*)d_in[23];
  const float* c2_s2p_Wr = (const float*)d_in[24];

  const int* src = eidx;        // pd ids
  const int* dst = eidx + EC;   // se ids
  const int* li0 = elidx;       // pd ids
  const int* li1 = elidx + LC;  // se ids

  char* ws = (char*)d_ws;
  size_t o = 0;
  auto alloc = [&](size_t bytes) -> char* {
    char* p = ws + o;
    o = (o + bytes + 255) & ~(size_t)255;
    return p;
  };
  // bf16 activations
  ushort* h_pd = (ushort*)alloc((size_t)NP * 64 * 2);
  ushort* h_se = (ushort*)alloc((size_t)NS * 64 * 2);
  ushort* pd1 = (ushort*)alloc((size_t)NP * 64 * 2);
  ushort* se1 = (ushort*)alloc((size_t)NS * 64 * 2);
  ushort* agg_pd = (ushort*)alloc((size_t)NP * 64 * 2);
  ushort* agg_se = (ushort*)alloc((size_t)NS * 64 * 2);
  // fp32 final features (classifier inputs)
  float* pd2 = (float*)alloc((size_t)NP * 64 * 4);
  float* se2 = (float*)alloc((size_t)NS * 64 * 4);
  int* col_se = (int*)alloc((size_t)EC * 4);
  int* col_pd = (int*)alloc((size_t)EC * 4);
  int* deg_se = (int*)alloc((size_t)NS * 4);
  int* deg_pd = (int*)alloc((size_t)NP * 4);
  int* rp_se = (int*)alloc((size_t)NS * 4);
  int* rp_pd = (int*)alloc((size_t)NP * 4);
  int* bcntS = (int*)alloc(1024);
  int* bcntP = (int*)alloc(1024);
  int* gbaseS = (int*)alloc(1024);
  int* gbaseP = (int*)alloc(1024);
  int* gcurS = (int*)alloc(1024);
  int* gcurP = (int*)alloc(1024);
  ushort* wt_pd = (ushort*)alloc((size_t)64 * 512 * 2);
  ushort* wt_se = (ushort*)alloc((size_t)64 * 768 * 2);
  ushort* wt_c1p2s = (ushort*)alloc((size_t)64 * 128 * 2);
  ushort* wt_c1s2p = (ushort*)alloc((size_t)64 * 128 * 2);
  ushort* wt_c2p2s = (ushort*)alloc((size_t)64 * 128 * 2);
  ushort* wt_c2s2p = (ushort*)alloc((size_t)64 * 128 * 2);

  // packed (node,nbr) tmp arrays alias pd2 (dead until layer-2 GEMM): 2*6.4MB < 25.6MB
  int* tmpS = (int*)pd2;
  int* tmpP = tmpS + EC;

  hipMemsetAsync(bcntS, 0, 1024, stream);
  hipMemsetAsync(bcntP, 0, 1024, stream);

  // CSR build (bucketed counting sort; shared by both layers)
  k_bcount<<<NBLK, 256, 0, stream>>>(src, dst, bcntS, bcntP, EC);
  k_bscan<<<1, 256, 0, stream>>>(bcntS, bcntP, gbaseS, gbaseP, gcurS, gcurP);
  k_bscatter<<<NBLK, 256, 0, stream>>>(src, dst, gcurS, gcurP, tmpS, tmpP, EC);
  k_bfinal<64, 17><<<NBS, 256, 0, stream>>>(tmpS, gbaseS, bcntS, SH_S, NS, rp_se,
                                            deg_se, col_se);
  k_bfinal<512, 14><<<NBP, 256, 0, stream>>>(tmpP, gbaseP, bcntP, SH_P, NP, rp_pd,
                                             deg_pd, col_pd);

  // weight transpose + bf16 cvt (10 jobs, one kernel)
  {
    WtJobs jobs;
    jobs.j[0] = {W_pd, wt_pd, 512, 512, 0};
    jobs.j[1] = {W_se, wt_se, 768, 768, 0};
    jobs.j[2] = {c1_p2s_Wl, wt_c1p2s, 64, 128, 0};
    jobs.j[3] = {c1_p2s_Wr, wt_c1p2s, 64, 128, 64};
    jobs.j[4] = {c1_s2p_Wl, wt_c1s2p, 64, 128, 0};
    jobs.j[5] = {c1_s2p_Wr, wt_c1s2p, 64, 128, 64};
    jobs.j[6] = {c2_p2s_Wl, wt_c2p2s, 64, 128, 0};
    jobs.j[7] = {c2_p2s_Wr, wt_c2p2s, 64, 128, 64};
    jobs.j[8] = {c2_s2p_Wl, wt_c2s2p, 64, 128, 0};
    jobs.j[9] = {c2_s2p_Wr, wt_c2s2p, 64, 128, 64};
    const int tot = 64 * (512 + 768 + 8 * 64);
    k_wt_all<<<(tot + 255) / 256, 256, 0, stream>>>(jobs);
  }

  const int gP = (NP + 63) / 64;  // 1563
  const int gS = (NS + 63) / 64;  // 157
  const int gAgg = (NS + NP) / 4; // 27500

  // input projections (MFMA, dual-job): h = bf16(x @ W + b + emb[nid])
  {
    GJob jp = {x_pd, nullptr, 512, 512, 0, 512, wt_pd, b_pd, emb_pd, nid_pd, h_pd, NP, gP};
    GJob js = {x_se, nullptr, 768, 768, 0, 768, wt_se, b_se, emb_se, nid_se, h_se, NS, gS};
    k_mgemm2<false, true, false, true><<<gP + gS, 256, 0, stream>>>(jp, js);
  }

  // layer 1 (relu): out = bf16(relu([mean | xd] @ [Wl;Wr] + bl))
  k_agg2<<<gAgg, 256, 0, stream>>>(h_pd, h_se, rp_se, deg_se, col_se, rp_pd, deg_pd,
                                   col_pd, agg_se, agg_pd);
  {
    GJob jp = {agg_pd, h_pd, 64, 64, 64, 128, wt_c1s2p, c1_s2p_bl, nullptr, nullptr, pd1, NP, gP};
    GJob js = {agg_se, h_se, 64, 64, 64, 128, wt_c1p2s, c1_p2s_bl, nullptr, nullptr, se1, NS, gS};
    k_mgemm2<true, false, true, true><<<gP + gS, 256, 0, stream>>>(jp, js);
  }

  // layer 2 (no act, fp32 out for classifier)
  k_agg2<<<gAgg, 256, 0, stream>>>(pd1, se1, rp_se, deg_se, col_se, rp_pd, deg_pd,
                                   col_pd, agg_se, agg_pd);
  {
    GJob jp = {agg_pd, pd1, 64, 64, 64, 128, wt_c2s2p, c2_s2p_bl, nullptr, nullptr, pd2, NP, gP};
    GJob js = {agg_se, se1, 64, 64, 64, 128, wt_c2p2s, c2_p2s_bl, nullptr, nullptr, se2, NS, gS};
    k_mgemm2<false, false, true, false><<<gP + gS, 256, 0, stream>>>(jp, js);
  }

  // classifier + label passthrough (fused)
  float* outF = (float*)d_out;
  const int nClsBlk = (LC + 15) / 16;
  const int nCpyBlk = (LC / 4 + 255) / 256;
  k_classify<<<nClsBlk + nCpyBlk, 256, 0, stream>>>(pd2, se2, li0, li1, elabel, outF,
                                                    LC, nClsBlk);
}